// Round 9
// baseline (514.123 us; speedup 1.0000x reference)
//
#include <hip/hip_runtime.h>
#include <math.h>

#define NNODES 50000
#define NEDGES 800000
#define NLAYERS 3
#define NHEADS 2
#define NCH 64
#define FDIM 128   // == NHEADS*NCH
#define NCLS 10
#define NGRAPH 64
#define NEG_SLOPE 0.2f
#define GEMMB ((NNODES + 63) / 64)    // 782
#define NB 391                        // buckets = ceil(50000/128)
#define RADB 391                      // radix blocks = ceil(800000/2048)
#define PCH 8                         // pool chunks per graph
#define AGG4 (NNODES / 4)             // 12500 blocks (4 nodes each)
#define QSZ ((size_t)NNODES * 16)     // dwords per quarter table

typedef __attribute__((ext_vector_type(8))) short bf16x8;
typedef __attribute__((ext_vector_type(4))) float f32x4;

__device__ __forceinline__ unsigned short f2bf(float f) {
  unsigned int u = __builtin_bit_cast(unsigned int, f);
  unsigned int r = u + 0x7FFFu + ((u >> 16) & 1u);  // RNE
  return (unsigned short)(r >> 16);
}
__device__ __forceinline__ float bflo(unsigned v) {
  return __builtin_bit_cast(float, v << 16);
}
__device__ __forceinline__ float bfhi(unsigned v) {
  return __builtin_bit_cast(float, v & 0xFFFF0000u);
}

// ---- W prep (3 blocks) + graph offsets / zero-init (1 block) --------------
__global__ __launch_bounds__(256) void k_wprep(const float* __restrict__ W,
                                               unsigned* __restrict__ Wt,
                                               const int* __restrict__ batch,
                                               int* __restrict__ goff,
                                               float* __restrict__ gsum,
                                               int* __restrict__ bcnt) {
  __shared__ float Lt[128][132];
  int l = blockIdx.x;
  int t = threadIdx.x;
  if (l == NLAYERS) {  // goff + zero gsum + zero bcnt
    if (t < NGRAPH) {
      int lo = 0, hi = NNODES;
      while (lo < hi) {
        int mid = (lo + hi) >> 1;
        if (batch[mid] < t) lo = mid + 1;
        else hi = mid;
      }
      goff[t] = lo;
    }
    if (t == 0) goff[NGRAPH] = NNODES;
    for (int i = t; i < NGRAPH * FDIM; i += 256) gsum[i] = 0.f;
    for (int i = t; i < NB; i += 256) bcnt[i] = 0;
    return;
  }
  const float* Wl = W + (size_t)l * FDIM * FDIM;
  unsigned* Wtl = Wt + (size_t)l * FDIM * FDIM / 2;
#pragma unroll
  for (int i = 0; i < 16; ++i) {
    int k = (t >> 5) + 8 * i;
    int n4 = (t & 31) * 4;
    float4 v = *(const float4*)(Wl + (size_t)k * 128 + n4);
    Lt[k][n4 + 0] = v.x;
    Lt[k][n4 + 1] = v.y;
    Lt[k][n4 + 2] = v.z;
    Lt[k][n4 + 3] = v.w;
  }
  __syncthreads();
  int n = t >> 1;
  int kh = (t & 1) * 64;
  for (int kk = 0; kk < 64; kk += 2) {
    unsigned pk = (unsigned)f2bf(Lt[kh + kk][n]) |
                  ((unsigned)f2bf(Lt[kh + kk + 1][n]) << 16);
    Wtl[n * 64 + (kh >> 1) + (kk >> 1)] = pk;
  }
}

// ---------------- MFMA GEMM body (no LDS) ----------------
// Writes H as 4 contiguous quarter tables Hb[q*QSZ + row*16 + l] where
// dword holds bf16 pair (h0[16q+l], h1[16q+l]); plus fused alphas.
__device__ __forceinline__ void gemm_body(int blk, const float* __restrict__ X,
                                          const unsigned* __restrict__ Wt,
                                          const float* __restrict__ a_sL,
                                          const float* __restrict__ a_dL,
                                          unsigned* __restrict__ Hb,
                                          float* __restrict__ as_,
                                          float* __restrict__ ad_) {
  int t = threadIdx.x;
  int lane = t & 63;
  int w = t >> 6;
  int row0 = blk * 64;
  int n16 = lane & 15;
  int quad = lane >> 4;
  int m0 = w * 16;

  int gr = row0 + m0 + n16;
  const float* xp = X + (size_t)min(gr, NNODES - 1) * 128;

  f32x4 acc[8];
#pragma unroll
  for (int nt = 0; nt < 8; ++nt) {
    f32x4 z = {0.f, 0.f, 0.f, 0.f};
    acc[nt] = z;
  }
#pragma unroll
  for (int kk = 0; kk < 4; ++kk) {
    float4 va = *(const float4*)(xp + kk * 32 + quad * 8);
    float4 vb = *(const float4*)(xp + kk * 32 + quad * 8 + 4);
    bf16x8 af;
    af[0] = (short)f2bf(va.x); af[1] = (short)f2bf(va.y);
    af[2] = (short)f2bf(va.z); af[3] = (short)f2bf(va.w);
    af[4] = (short)f2bf(vb.x); af[5] = (short)f2bf(vb.y);
    af[6] = (short)f2bf(vb.z); af[7] = (short)f2bf(vb.w);
#pragma unroll
    for (int nt = 0; nt < 8; ++nt) {
      bf16x8 bf = *(const bf16x8*)(Wt + (size_t)(nt * 16 + n16) * 64 +
                                   kk * 16 + quad * 4);
      acc[nt] =
          __builtin_amdgcn_mfma_f32_16x16x32_bf16(af, bf, acc[nt], 0, 0, 0);
    }
  }

  float asv[8], adv[8];
#pragma unroll
  for (int nt = 0; nt < 8; ++nt) {
    asv[nt] = a_sL[nt * 16 + n16];
    adv[nt] = a_dL[nt * 16 + n16];
  }
#pragma unroll
  for (int r = 0; r < 4; ++r) {
    int row = row0 + m0 + quad * 4 + r;
    bool ok = (row < NNODES);
    float ps0 = 0.f, pd0 = 0.f, ps1 = 0.f, pd1 = 0.f;
#pragma unroll
    for (int nt = 0; nt < 4; ++nt) {
      ps0 += acc[nt][r] * asv[nt];
      pd0 += acc[nt][r] * adv[nt];
      ps1 += acc[nt + 4][r] * asv[nt + 4];
      pd1 += acc[nt + 4][r] * adv[nt + 4];
    }
#pragma unroll
    for (int off = 1; off < 16; off <<= 1) {
      ps0 += __shfl_xor(ps0, off, 64);
      pd0 += __shfl_xor(pd0, off, 64);
      ps1 += __shfl_xor(ps1, off, 64);
      pd1 += __shfl_xor(pd1, off, 64);
    }
    if (ok && n16 == 0) {
      as_[row * 2 + 0] = ps0;
      as_[row * 2 + 1] = ps1;
      ad_[row * 2 + 0] = pd0;
      ad_[row * 2 + 1] = pd1;
    }
    if (ok) {
#pragma unroll
      for (int nt = 0; nt < 4; ++nt) {
        unsigned pk = (unsigned)f2bf(acc[nt][r]) |
                      ((unsigned)f2bf(acc[nt + 4][r]) << 16);
        Hb[(size_t)nt * QSZ + (size_t)row * 16 + n16] = pk;
      }
    }
  }
}

__global__ __launch_bounds__(256) void k_gemm(const float* __restrict__ X,
                                              const unsigned* __restrict__ Wt,
                                              const float* __restrict__ a_sL,
                                              const float* __restrict__ a_dL,
                                              unsigned* __restrict__ Hb,
                                              float* __restrict__ as_,
                                              float* __restrict__ ad_) {
  gemm_body(blockIdx.x, X, Wt, a_sL, a_dL, Hb, as_, ad_);
}

// fused: layer-0 GEMM | radix pass A (LDS hist + return-atomic block bases).
__global__ __launch_bounds__(256) void k_front(
    const float* __restrict__ X, const unsigned* __restrict__ Wt,
    const float* __restrict__ a_sL, const float* __restrict__ a_dL,
    unsigned* __restrict__ Hb, float* __restrict__ as_,
    float* __restrict__ ad_, const int* __restrict__ ei, int* __restrict__ bh,
    int* __restrict__ bcnt) {
  int b = blockIdx.x;
  if (b < GEMMB) {
    gemm_body(b, X, Wt, a_sL, a_dL, Hb, as_, ad_);
  } else {
    __shared__ int hist[NB];
    int blk = b - GEMMB;
    int t = threadIdx.x;
    for (int i = t; i < NB; i += 256) hist[i] = 0;
    __syncthreads();
    int e0 = blk * 2048;
#pragma unroll
    for (int i = 0; i < 8; ++i) {
      int e = e0 + i * 256 + t;
      if (e < NEDGES) atomicAdd(&hist[ei[NEDGES + e] >> 7], 1);
    }
    __syncthreads();
    for (int i = t; i < NB; i += 256) {
      int c = hist[i];
      int base = c ? atomicAdd(&bcnt[i], c) : 0;
      bh[i * RADB + blk] = base;
    }
  }
}

// ---------------- single-block exclusive scan of bucket totals ----------
__global__ __launch_bounds__(256) void k_bscan(const int* __restrict__ bcnt,
                                               int* __restrict__ bstart) {
  __shared__ int ps[256];
  int t = threadIdx.x;
  int x0 = (2 * t < NB) ? bcnt[2 * t] : 0;
  int x1 = (2 * t + 1 < NB) ? bcnt[2 * t + 1] : 0;
  int pair = x0 + x1;
  ps[t] = pair;
  __syncthreads();
  for (int off = 1; off < 256; off <<= 1) {
    int v = (t >= off) ? ps[t - off] : 0;
    __syncthreads();
    ps[t] += v;
    __syncthreads();
  }
  int ex = ps[t] - pair;
  if (2 * t < NB) bstart[2 * t] = ex;
  if (2 * t + 1 < NB) bstart[2 * t + 1] = ex + x0;
  if (t == 0) bstart[NB] = NEDGES;
}

// ---------------- radix pass B ----------------
__global__ __launch_bounds__(256) void k_passB(const int* __restrict__ ei,
                                               const int* __restrict__ bstart,
                                               const int* __restrict__ bh,
                                               unsigned* __restrict__ ebuf) {
  __shared__ int curs[NB];
  int blk = blockIdx.x, t = threadIdx.x;
  for (int i = t; i < NB; i += 256) curs[i] = bstart[i] + bh[i * RADB + blk];
  __syncthreads();
  int e0 = blk * 2048;
#pragma unroll
  for (int i = 0; i < 8; ++i) {
    int e = e0 + i * 256 + t;
    if (e < NEDGES) {
      int s = ei[e];
      int d = ei[NEDGES + e];
      int pos = atomicAdd(&curs[d >> 7], 1);
      ebuf[pos] = ((unsigned)s << 7) | (unsigned)(d & 127);
    }
  }
}

// ---------------- radix pass C ----------------
__global__ __launch_bounds__(256) void k_passC(const unsigned* __restrict__ ebuf,
                                               const int* __restrict__ bstart,
                                               int* __restrict__ row_ptr,
                                               int* __restrict__ csr) {
  __shared__ int deg[128];
  __shared__ int scn[128];
  int b = blockIdx.x, t = threadIdx.x;
  int node0 = b * 128;
  int nn = min(128, NNODES - node0);
  int estart = bstart[b];
  int eend = bstart[b + 1];
  if (t < 128) deg[t] = 0;
  __syncthreads();
  for (int e = estart + t; e < eend; e += 256)
    atomicAdd(&deg[ebuf[e] & 127], 1);
  __syncthreads();
  if (t < 128) scn[t] = (t < nn) ? deg[t] + 1 : 0;
  __syncthreads();
  for (int off = 1; off < 128; off <<= 1) {
    int v = (t < 128 && t >= off) ? scn[t - off] : 0;
    __syncthreads();
    if (t < 128) scn[t] += v;
    __syncthreads();
  }
  int base = estart + node0;
  if (t < nn) {
    int st = base + (t ? scn[t - 1] : 0);
    row_ptr[node0 + t] = st;
    csr[st] = node0 + t;  // self-loop at rank 0
    deg[t] = st + 1;      // reuse as cursor
  }
  if (b == 0 && t == 0) row_ptr[NNODES] = NEDGES + NNODES;
  __syncthreads();
  for (int e = estart + t; e < eend; e += 256) {
    unsigned v = ebuf[e];
    int pos = atomicAdd(&deg[v & 127], 1);
    csr[pos] = (int)(v >> 7);
  }
}

// ---------------- softmax precompute: p per edge, 1/z per node ----------
__global__ __launch_bounds__(256) void k_softmax(
    const float* __restrict__ as_, const float* __restrict__ ad_,
    const int* __restrict__ row_ptr, const int* __restrict__ csr,
    float2* __restrict__ pe, float2* __restrict__ zinv) {
  int wv = threadIdx.x >> 6;
  int lane = threadIdx.x & 63;
  int node = blockIdx.x * 4 + wv;
  if (node >= NNODES) return;
  int rs = row_ptr[node], re = row_ptr[node + 1];
  float2 adv = *(const float2*)&ad_[node * 2];
  float z0 = 0.f, z1 = 0.f;
  for (int j = rs + lane; j < re; j += 64) {
    int s = csr[j];
    float2 asv = *(const float2*)&as_[s * 2];
    float e0 = asv.x + adv.x; e0 = (e0 > 0.f) ? e0 : NEG_SLOPE * e0;
    float e1 = asv.y + adv.y; e1 = (e1 > 0.f) ? e1 : NEG_SLOPE * e1;
    float p0 = __expf(e0);
    float p1 = __expf(e1);
    z0 += p0;
    z1 += p1;
    pe[j] = make_float2(p0, p1);
  }
#pragma unroll
  for (int off = 32; off > 0; off >>= 1) {
    z0 += __shfl_xor(z0, off, 64);
    z1 += __shfl_xor(z1, off, 64);
  }
  if (lane == 0) zinv[node] = make_float2(1.f / z0, 1.f / z1);
}

// ---------------- gather: 4 channel-quarter phases, 16 lanes/edge ---------
// phase q = blockIdx/AGG4; each phase's 3.2 MB quarter table is ~L2-resident.
__global__ __launch_bounds__(256) void k_gather(
    const unsigned* __restrict__ Hb, const float2* __restrict__ pe,
    const float2* __restrict__ zinv, const int* __restrict__ row_ptr,
    const int* __restrict__ csr, const float* __restrict__ bias,
    float* __restrict__ Xout) {
  int q = blockIdx.x / AGG4;
  int blk = blockIdx.x - q * AGG4;
  int wv = threadIdx.x >> 6;
  int lane = threadIdx.x & 63;
  int node = blk * 4 + wv;
  int rs = row_ptr[node], re = row_ptr[node + 1];
  int g = lane >> 4, l = lane & 15;
  const unsigned* Ht = Hb + (size_t)q * QSZ + l;
  float ax = 0.f, ay = 0.f;
  for (int j0 = rs; j0 < re; j0 += 8) {  // 8 edges in flight (2 per group)
    int ja = j0 + g;
    int jb = j0 + 4 + g;
    bool va = ja < re, vb = jb < re;
    int jja = va ? ja : rs;
    int jjb = vb ? jb : rs;
    int sa = csr[jja];
    int sb_ = csr[jjb];
    float2 pa = pe[jja];
    float2 pb = pe[jjb];
    unsigned ha = Ht[(size_t)sa * 16];
    unsigned hb2 = Ht[(size_t)sb_ * 16];
    if (!va) { pa.x = 0.f; pa.y = 0.f; }
    if (!vb) { pb.x = 0.f; pb.y = 0.f; }
    ax += pa.x * bflo(ha);
    ay += pa.y * bfhi(ha);
    ax += pb.x * bflo(hb2);
    ay += pb.y * bfhi(hb2);
  }
  ax += __shfl_xor(ax, 16, 64);
  ay += __shfl_xor(ay, 16, 64);
  ax += __shfl_xor(ax, 32, 64);
  ay += __shfl_xor(ay, 32, 64);
  if (g == 0) {
    float2 zi = zinv[node];
    int c = q * 16 + l;
    float o0 = ax * zi.x + bias[c];
    float o1 = ay * zi.y + bias[64 + c];
    o0 = (o0 > 0.f) ? o0 : expm1f(o0);  // ELU
    o1 = (o1 > 0.f) ? o1 : expm1f(o1);
    Xout[(size_t)node * 128 + c] = o0;
    Xout[(size_t)node * 128 + 64 + c] = o1;
  }
}

// ---------------- pooling: 8 chunks/graph, coalesced contiguous rows ------
__global__ __launch_bounds__(256) void k_pool2(const float* __restrict__ Xf,
                                               const int* __restrict__ goff,
                                               float* __restrict__ gsum) {
  __shared__ float red[128];
  int b = blockIdx.x;
  int g = b >> 3, ch = b & 7;
  int t = threadIdx.x;
  int c = t & 127, rh = t >> 7;
  int s = goff[g], e = goff[g + 1];
  int len = e - s;
  int c0 = s + (len * ch) / PCH;
  int c1 = s + (len * (ch + 1)) / PCH;
  float acc = 0.f;
  for (int n = c0 + rh; n < c1; n += 2) acc += Xf[(size_t)n * 128 + c];
  if (rh) red[c] = acc;
  __syncthreads();
  if (!rh) atomicAdd(&gsum[g * FDIM + c], acc + red[c]);
}

// ---------------- classifier ----------------
__global__ __launch_bounds__(64) void k_final(const float* __restrict__ gsum,
                                              const int* __restrict__ goff,
                                              const float* __restrict__ lw,
                                              const float* __restrict__ lb,
                                              float* __restrict__ out) {
  int g = threadIdx.x;
  float cnt = (float)(goff[g + 1] - goff[g]);
  float inv = 1.f / fmaxf(cnt, 1.f);
  float lg[NCLS];
#pragma unroll
  for (int k = 0; k < NCLS; ++k) lg[k] = lb[k];
  for (int c = 0; c < FDIM; ++c) {
    float pv = gsum[g * FDIM + c] * inv;
#pragma unroll
    for (int k = 0; k < NCLS; ++k) lg[k] += pv * lw[c * NCLS + k];
  }
  float mx = lg[0];
#pragma unroll
  for (int k = 1; k < NCLS; ++k) mx = fmaxf(mx, lg[k]);
  float s = 0.f;
#pragma unroll
  for (int k = 0; k < NCLS; ++k) {
    lg[k] = expf(lg[k] - mx);
    s += lg[k];
  }
  float invs = 1.f / s;
#pragma unroll
  for (int k = 0; k < NCLS; ++k) out[g * NCLS + k] = lg[k] * invs;
}

// ---------------- launch ----------------

extern "C" void kernel_launch(void* const* d_in, const int* in_sizes, int n_in,
                              void* d_out, int out_size, void* d_ws,
                              size_t ws_size, hipStream_t stream) {
  const float* x = (const float*)d_in[0];
  const int* ei = (const int*)d_in[1];
  const int* batch = (const int*)d_in[2];
  const float* W = (const float*)d_in[3];
  const float* a_s = (const float*)d_in[4];
  const float* a_d = (const float*)d_in[5];
  const float* bias = (const float*)d_in[6];
  const float* lw = (const float*)d_in[7];
  const float* lb = (const float*)d_in[8];
  float* out = (float*)d_out;

  unsigned* Hb = (unsigned*)d_ws;                  // N*64 (4 quarter tables)
  float* xb = (float*)(Hb + (size_t)NNODES * 64);  // N*128
  float* as_ = xb + (size_t)NNODES * 128;          // N*2
  float* ad_ = as_ + (size_t)NNODES * 2;           // N*2
  float2* pe = (float2*)(ad_ + (size_t)NNODES * 2);  // E+N float2
  float2* zinv = pe + (NEDGES + NNODES);           // N float2
  float* gsum = (float*)(zinv + NNODES);           // 64*128
  int* goff = (int*)(gsum + NGRAPH * FDIM);        // 65
  int* bcnt = goff + (NGRAPH + 1);                 // NB
  int* bstart = bcnt + NB;                         // NB+1
  int* row_ptr = bstart + (NB + 1);                // N+1
  int* csr = row_ptr + (NNODES + 1);               // E+N
  int* bh = csr + (NEDGES + NNODES);               // NB*RADB
  unsigned* ebuf = (unsigned*)(bh + NB * RADB);    // E (+pad)
  unsigned* Wt = ebuf + (NEDGES + 1024);           // 3*8192 (bf16 W^T)

  k_wprep<<<NLAYERS + 1, 256, 0, stream>>>(W, Wt, batch, goff, gsum, bcnt);
  // layer-0 GEMM overlapped with radix pass A
  k_front<<<GEMMB + RADB, 256, 0, stream>>>(x, Wt, a_s, a_d, Hb, as_, ad_, ei,
                                            bh, bcnt);
  k_bscan<<<1, 256, 0, stream>>>(bcnt, bstart);
  k_passB<<<RADB, 256, 0, stream>>>(ei, bstart, bh, ebuf);
  k_passC<<<NB, 256, 0, stream>>>(ebuf, bstart, row_ptr, csr);

  for (int l = 0; l < NLAYERS; ++l) {
    if (l > 0) {
      k_gemm<<<GEMMB, 256, 0, stream>>>(xb, Wt + (size_t)l * FDIM * FDIM / 2,
                                        a_s + l * FDIM, a_d + l * FDIM, Hb,
                                        as_, ad_);
    }
    k_softmax<<<AGG4, 256, 0, stream>>>(as_, ad_, row_ptr, csr, pe, zinv);
    k_gather<<<4 * AGG4, 256, 0, stream>>>(Hb, pe, zinv, row_ptr, csr,
                                           bias + l * FDIM, xb);
  }
  k_pool2<<<NGRAPH * PCH, 256, 0, stream>>>(xb, goff, gsum);
  k_final<<<1, 64, 0, stream>>>(gsum, goff, lw, lb, out);
}

// Round 10
// 315.516 us; speedup vs baseline: 1.6295x; 1.6295x over previous
//
#include <hip/hip_runtime.h>
#include <math.h>

#define NNODES 50000
#define NEDGES 800000
#define NLAYERS 3
#define NHEADS 2
#define NCH 64
#define FDIM 128   // == NHEADS*NCH
#define NCLS 10
#define NGRAPH 64
#define NEG_SLOPE 0.2f
#define GEMMB ((NNODES + 63) / 64)    // 782
#define NB 391                        // buckets = ceil(50000/128)
#define RADB 391                      // radix blocks = ceil(800000/2048)
#define PCH 8                         // pool chunks per graph

#define WAVE_SYNC()                      \
  do {                                   \
    __builtin_amdgcn_wave_barrier();     \
    __asm__ volatile("" ::: "memory");   \
  } while (0)

typedef __attribute__((ext_vector_type(8))) short bf16x8;
typedef __attribute__((ext_vector_type(4))) float f32x4;

__device__ __forceinline__ unsigned short f2bf(float f) {
  unsigned int u = __builtin_bit_cast(unsigned int, f);
  unsigned int r = u + 0x7FFFu + ((u >> 16) & 1u);  // RNE
  return (unsigned short)(r >> 16);
}
__device__ __forceinline__ float bflo(unsigned v) {
  return __builtin_bit_cast(float, v << 16);
}
__device__ __forceinline__ float bfhi(unsigned v) {
  return __builtin_bit_cast(float, v & 0xFFFF0000u);
}

// ---- W prep (3 blocks) + graph offsets / zero-init (1 block) --------------
__global__ __launch_bounds__(256) void k_wprep(const float* __restrict__ W,
                                               unsigned* __restrict__ Wt,
                                               const int* __restrict__ batch,
                                               int* __restrict__ goff,
                                               float* __restrict__ gsum,
                                               int* __restrict__ bcnt) {
  __shared__ float Lt[128][132];
  int l = blockIdx.x;
  int t = threadIdx.x;
  if (l == NLAYERS) {  // goff + zero gsum + zero bcnt
    if (t < NGRAPH) {
      int lo = 0, hi = NNODES;
      while (lo < hi) {
        int mid = (lo + hi) >> 1;
        if (batch[mid] < t) lo = mid + 1;
        else hi = mid;
      }
      goff[t] = lo;
    }
    if (t == 0) goff[NGRAPH] = NNODES;
    for (int i = t; i < NGRAPH * FDIM; i += 256) gsum[i] = 0.f;
    for (int i = t; i < NB; i += 256) bcnt[i] = 0;
    return;
  }
  const float* Wl = W + (size_t)l * FDIM * FDIM;
  unsigned* Wtl = Wt + (size_t)l * FDIM * FDIM / 2;
#pragma unroll
  for (int i = 0; i < 16; ++i) {
    int k = (t >> 5) + 8 * i;
    int n4 = (t & 31) * 4;
    float4 v = *(const float4*)(Wl + (size_t)k * 128 + n4);
    Lt[k][n4 + 0] = v.x;
    Lt[k][n4 + 1] = v.y;
    Lt[k][n4 + 2] = v.z;
    Lt[k][n4 + 3] = v.w;
  }
  __syncthreads();
  int n = t >> 1;
  int kh = (t & 1) * 64;
  for (int kk = 0; kk < 64; kk += 2) {
    unsigned pk = (unsigned)f2bf(Lt[kh + kk][n]) |
                  ((unsigned)f2bf(Lt[kh + kk + 1][n]) << 16);
    Wtl[n * 64 + (kh >> 1) + (kk >> 1)] = pk;
  }
}

// ---------------- MFMA GEMM body (no LDS) ----------------
// H[row,:] = X[row,:] @ W. Hb dword d of row holds bf16 pair (h0[d], h1[d]).
__device__ __forceinline__ void gemm_body(int blk, const float* __restrict__ X,
                                          const unsigned* __restrict__ Wt,
                                          const float* __restrict__ a_sL,
                                          const float* __restrict__ a_dL,
                                          unsigned* __restrict__ Hb,
                                          float* __restrict__ as_,
                                          float* __restrict__ ad_) {
  int t = threadIdx.x;
  int lane = t & 63;
  int w = t >> 6;
  int row0 = blk * 64;
  int n16 = lane & 15;
  int quad = lane >> 4;
  int m0 = w * 16;

  int gr = row0 + m0 + n16;
  const float* xp = X + (size_t)min(gr, NNODES - 1) * 128;

  f32x4 acc[8];
#pragma unroll
  for (int nt = 0; nt < 8; ++nt) {
    f32x4 z = {0.f, 0.f, 0.f, 0.f};
    acc[nt] = z;
  }
#pragma unroll
  for (int kk = 0; kk < 4; ++kk) {
    float4 va = *(const float4*)(xp + kk * 32 + quad * 8);
    float4 vb = *(const float4*)(xp + kk * 32 + quad * 8 + 4);
    bf16x8 af;
    af[0] = (short)f2bf(va.x); af[1] = (short)f2bf(va.y);
    af[2] = (short)f2bf(va.z); af[3] = (short)f2bf(va.w);
    af[4] = (short)f2bf(vb.x); af[5] = (short)f2bf(vb.y);
    af[6] = (short)f2bf(vb.z); af[7] = (short)f2bf(vb.w);
#pragma unroll
    for (int nt = 0; nt < 8; ++nt) {
      bf16x8 bf = *(const bf16x8*)(Wt + (size_t)(nt * 16 + n16) * 64 +
                                   kk * 16 + quad * 4);
      acc[nt] =
          __builtin_amdgcn_mfma_f32_16x16x32_bf16(af, bf, acc[nt], 0, 0, 0);
    }
  }

  float asv[8], adv[8];
#pragma unroll
  for (int nt = 0; nt < 8; ++nt) {
    asv[nt] = a_sL[nt * 16 + n16];
    adv[nt] = a_dL[nt * 16 + n16];
  }
#pragma unroll
  for (int r = 0; r < 4; ++r) {
    int row = row0 + m0 + quad * 4 + r;
    bool ok = (row < NNODES);
    float ps0 = 0.f, pd0 = 0.f, ps1 = 0.f, pd1 = 0.f;
#pragma unroll
    for (int nt = 0; nt < 4; ++nt) {
      ps0 += acc[nt][r] * asv[nt];
      pd0 += acc[nt][r] * adv[nt];
      ps1 += acc[nt + 4][r] * asv[nt + 4];
      pd1 += acc[nt + 4][r] * adv[nt + 4];
    }
#pragma unroll
    for (int off = 1; off < 16; off <<= 1) {
      ps0 += __shfl_xor(ps0, off, 64);
      pd0 += __shfl_xor(pd0, off, 64);
      ps1 += __shfl_xor(ps1, off, 64);
      pd1 += __shfl_xor(pd1, off, 64);
    }
    if (ok && n16 == 0) {
      as_[row * 2 + 0] = ps0;
      as_[row * 2 + 1] = ps1;
      ad_[row * 2 + 0] = pd0;
      ad_[row * 2 + 1] = pd1;
    }
    if (ok) {
#pragma unroll
      for (int nt = 0; nt < 4; ++nt) {
        unsigned pk = (unsigned)f2bf(acc[nt][r]) |
                      ((unsigned)f2bf(acc[nt + 4][r]) << 16);
        Hb[(size_t)row * 64 + nt * 16 + n16] = pk;
      }
    }
  }
}

__global__ __launch_bounds__(256) void k_gemm(const float* __restrict__ X,
                                              const unsigned* __restrict__ Wt,
                                              const float* __restrict__ a_sL,
                                              const float* __restrict__ a_dL,
                                              unsigned* __restrict__ Hb,
                                              float* __restrict__ as_,
                                              float* __restrict__ ad_) {
  gemm_body(blockIdx.x, X, Wt, a_sL, a_dL, Hb, as_, ad_);
}

// fused: layer-0 GEMM | radix pass A (LDS hist + return-atomic block bases).
__global__ __launch_bounds__(256) void k_front(
    const float* __restrict__ X, const unsigned* __restrict__ Wt,
    const float* __restrict__ a_sL, const float* __restrict__ a_dL,
    unsigned* __restrict__ Hb, float* __restrict__ as_,
    float* __restrict__ ad_, const int* __restrict__ ei, int* __restrict__ bh,
    int* __restrict__ bcnt) {
  int b = blockIdx.x;
  if (b < GEMMB) {
    gemm_body(b, X, Wt, a_sL, a_dL, Hb, as_, ad_);
  } else {
    __shared__ int hist[NB];
    int blk = b - GEMMB;
    int t = threadIdx.x;
    for (int i = t; i < NB; i += 256) hist[i] = 0;
    __syncthreads();
    int e0 = blk * 2048;
#pragma unroll
    for (int i = 0; i < 8; ++i) {
      int e = e0 + i * 256 + t;
      if (e < NEDGES) atomicAdd(&hist[ei[NEDGES + e] >> 7], 1);
    }
    __syncthreads();
    for (int i = t; i < NB; i += 256) {
      int c = hist[i];
      int base = c ? atomicAdd(&bcnt[i], c) : 0;
      bh[i * RADB + blk] = base;
    }
  }
}

// ---------------- single-block exclusive scan of bucket totals ----------
__global__ __launch_bounds__(256) void k_bscan(const int* __restrict__ bcnt,
                                               int* __restrict__ bstart) {
  __shared__ int ps[256];
  int t = threadIdx.x;
  int x0 = (2 * t < NB) ? bcnt[2 * t] : 0;
  int x1 = (2 * t + 1 < NB) ? bcnt[2 * t + 1] : 0;
  int pair = x0 + x1;
  ps[t] = pair;
  __syncthreads();
  for (int off = 1; off < 256; off <<= 1) {
    int v = (t >= off) ? ps[t - off] : 0;
    __syncthreads();
    ps[t] += v;
    __syncthreads();
  }
  int ex = ps[t] - pair;
  if (2 * t < NB) bstart[2 * t] = ex;
  if (2 * t + 1 < NB) bstart[2 * t + 1] = ex + x0;
  if (t == 0) bstart[NB] = NEDGES;
}

// ---------------- radix pass B ----------------
__global__ __launch_bounds__(256) void k_passB(const int* __restrict__ ei,
                                               const int* __restrict__ bstart,
                                               const int* __restrict__ bh,
                                               unsigned* __restrict__ ebuf) {
  __shared__ int curs[NB];
  int blk = blockIdx.x, t = threadIdx.x;
  for (int i = t; i < NB; i += 256) curs[i] = bstart[i] + bh[i * RADB + blk];
  __syncthreads();
  int e0 = blk * 2048;
#pragma unroll
  for (int i = 0; i < 8; ++i) {
    int e = e0 + i * 256 + t;
    if (e < NEDGES) {
      int s = ei[e];
      int d = ei[NEDGES + e];
      int pos = atomicAdd(&curs[d >> 7], 1);
      ebuf[pos] = ((unsigned)s << 7) | (unsigned)(d & 127);
    }
  }
}

// ---------------- radix pass C ----------------
__global__ __launch_bounds__(256) void k_passC(const unsigned* __restrict__ ebuf,
                                               const int* __restrict__ bstart,
                                               int* __restrict__ row_ptr,
                                               int* __restrict__ csr) {
  __shared__ int deg[128];
  __shared__ int scn[128];
  int b = blockIdx.x, t = threadIdx.x;
  int node0 = b * 128;
  int nn = min(128, NNODES - node0);
  int estart = bstart[b];
  int eend = bstart[b + 1];
  if (t < 128) deg[t] = 0;
  __syncthreads();
  for (int e = estart + t; e < eend; e += 256)
    atomicAdd(&deg[ebuf[e] & 127], 1);
  __syncthreads();
  if (t < 128) scn[t] = (t < nn) ? deg[t] + 1 : 0;
  __syncthreads();
  for (int off = 1; off < 128; off <<= 1) {
    int v = (t < 128 && t >= off) ? scn[t - off] : 0;
    __syncthreads();
    if (t < 128) scn[t] += v;
    __syncthreads();
  }
  int base = estart + node0;
  if (t < nn) {
    int st = base + (t ? scn[t - 1] : 0);
    row_ptr[node0 + t] = st;
    csr[st] = node0 + t;  // self-loop at rank 0
    deg[t] = st + 1;      // reuse as cursor
  }
  if (b == 0 && t == 0) row_ptr[NNODES] = NEDGES + NNODES;
  __syncthreads();
  for (int e = estart + t; e < eend; e += 256) {
    unsigned v = ebuf[e];
    int pos = atomicAdd(&deg[v & 127], 1);
    csr[pos] = (int)(v >> 7);
  }
}

// One wave per node: softmax + aggregation, software-pipelined gather
// (8-load batches, next batch issued before current consumed -> 16 in flight).
__global__ __launch_bounds__(256) void k_aggregate(
    const unsigned* __restrict__ Hb, const float* __restrict__ as_,
    const float* __restrict__ ad_, const int* __restrict__ row_ptr,
    const int* __restrict__ csr, const float* __restrict__ bias,
    float* __restrict__ Xout) {
  __shared__ float2 wb[4][64];
  __shared__ int sb[4][64];
  int wv = threadIdx.x >> 6;
  int lane = threadIdx.x & 63;
  int node = blockIdx.x * 4 + wv;
  if (node >= NNODES) return;
  int rs = row_ptr[node], re = row_ptr[node + 1];
  float2 adv = *(const float2*)&ad_[node * 2];
  const unsigned* Hl = Hb + lane;

  float z0 = 0.f, z1 = 0.f, acc0 = 0.f, acc1 = 0.f;
  for (int base = rs; base < re; base += 64) {
    int j = base + lane;
    float p0 = 0.f, p1 = 0.f;
    int s = 0;
    if (j < re) {
      s = csr[j];
      float2 asv = *(const float2*)&as_[s * 2];
      float e0 = asv.x + adv.x; e0 = (e0 > 0.f) ? e0 : NEG_SLOPE * e0;
      float e1 = asv.y + adv.y; e1 = (e1 > 0.f) ? e1 : NEG_SLOPE * e1;
      p0 = __expf(e0);
      p1 = __expf(e1);
    }
    z0 += p0;
    z1 += p1;
    wb[wv][lane] = make_float2(p0, p1);  // slots >= cl carry p=0, s=0
    sb[wv][lane] = s;
    WAVE_SYNC();
    int cl = min(64, re - base);
    int cl8 = (cl + 7) & ~7;  // zero-padded to batch multiple
    unsigned va[8];
#pragma unroll
    for (int u = 0; u < 8; ++u) va[u] = Hl[(size_t)sb[wv][u] * 64];
    int jj = 8;
    for (; jj < cl8; jj += 8) {
      unsigned vb2[8];
#pragma unroll
      for (int u = 0; u < 8; ++u) vb2[u] = Hl[(size_t)sb[wv][jj + u] * 64];
#pragma unroll
      for (int u = 0; u < 8; ++u) {
        float2 w = wb[wv][jj - 8 + u];
        acc0 += w.x * bflo(va[u]);
        acc1 += w.y * bfhi(va[u]);
      }
#pragma unroll
      for (int u = 0; u < 8; ++u) va[u] = vb2[u];
    }
#pragma unroll
    for (int u = 0; u < 8; ++u) {
      float2 w = wb[wv][jj - 8 + u];
      acc0 += w.x * bflo(va[u]);
      acc1 += w.y * bfhi(va[u]);
    }
    WAVE_SYNC();
  }
#pragma unroll
  for (int off = 32; off > 0; off >>= 1) {
    z0 += __shfl_xor(z0, off, 64);
    z1 += __shfl_xor(z1, off, 64);
  }
  float o0 = acc0 / z0 + bias[lane];
  float o1 = acc1 / z1 + bias[64 + lane];
  o0 = (o0 > 0.f) ? o0 : expm1f(o0);  // ELU
  o1 = (o1 > 0.f) ? o1 : expm1f(o1);
  Xout[(size_t)node * 128 + lane] = o0;
  Xout[(size_t)node * 128 + 64 + lane] = o1;
}

// ---------------- pooling: 8 chunks/graph, coalesced contiguous rows ------
__global__ __launch_bounds__(256) void k_pool2(const float* __restrict__ Xf,
                                               const int* __restrict__ goff,
                                               float* __restrict__ gsum) {
  __shared__ float red[128];
  int b = blockIdx.x;
  int g = b >> 3, ch = b & 7;
  int t = threadIdx.x;
  int c = t & 127, rh = t >> 7;
  int s = goff[g], e = goff[g + 1];
  int len = e - s;
  int c0 = s + (len * ch) / PCH;
  int c1 = s + (len * (ch + 1)) / PCH;
  float acc = 0.f;
  for (int n = c0 + rh; n < c1; n += 2) acc += Xf[(size_t)n * 128 + c];
  if (rh) red[c] = acc;
  __syncthreads();
  if (!rh) atomicAdd(&gsum[g * FDIM + c], acc + red[c]);
}

// ---------------- classifier ----------------
__global__ __launch_bounds__(64) void k_final(const float* __restrict__ gsum,
                                              const int* __restrict__ goff,
                                              const float* __restrict__ lw,
                                              const float* __restrict__ lb,
                                              float* __restrict__ out) {
  int g = threadIdx.x;
  float cnt = (float)(goff[g + 1] - goff[g]);
  float inv = 1.f / fmaxf(cnt, 1.f);
  float lg[NCLS];
#pragma unroll
  for (int k = 0; k < NCLS; ++k) lg[k] = lb[k];
  for (int c = 0; c < FDIM; ++c) {
    float pv = gsum[g * FDIM + c] * inv;
#pragma unroll
    for (int k = 0; k < NCLS; ++k) lg[k] += pv * lw[c * NCLS + k];
  }
  float mx = lg[0];
#pragma unroll
  for (int k = 1; k < NCLS; ++k) mx = fmaxf(mx, lg[k]);
  float s = 0.f;
#pragma unroll
  for (int k = 0; k < NCLS; ++k) {
    lg[k] = expf(lg[k] - mx);
    s += lg[k];
  }
  float invs = 1.f / s;
#pragma unroll
  for (int k = 0; k < NCLS; ++k) out[g * NCLS + k] = lg[k] * invs;
}

// ---------------- launch ----------------

extern "C" void kernel_launch(void* const* d_in, const int* in_sizes, int n_in,
                              void* d_out, int out_size, void* d_ws,
                              size_t ws_size, hipStream_t stream) {
  const float* x = (const float*)d_in[0];
  const int* ei = (const int*)d_in[1];
  const int* batch = (const int*)d_in[2];
  const float* W = (const float*)d_in[3];
  const float* a_s = (const float*)d_in[4];
  const float* a_d = (const float*)d_in[5];
  const float* bias = (const float*)d_in[6];
  const float* lw = (const float*)d_in[7];
  const float* lb = (const float*)d_in[8];
  float* out = (float*)d_out;

  unsigned* Hb = (unsigned*)d_ws;                  // N*64 packed bf16 pairs
  float* xb = (float*)(Hb + (size_t)NNODES * 64);  // N*128
  float* as_ = xb + (size_t)NNODES * 128;          // N*2
  float* ad_ = as_ + (size_t)NNODES * 2;           // N*2
  float* gsum = ad_ + (size_t)NNODES * 2;          // 64*128
  int* goff = (int*)(gsum + NGRAPH * FDIM);        // 65
  int* bcnt = goff + (NGRAPH + 1);                 // NB
  int* bstart = bcnt + NB;                         // NB+1
  int* row_ptr = bstart + (NB + 1);                // N+1
  int* csr = row_ptr + (NNODES + 1);               // E+N
  int* bh = csr + (NEDGES + NNODES);               // NB*RADB
  unsigned* ebuf = (unsigned*)(bh + NB * RADB);    // E (+pad)
  unsigned* Wt = ebuf + (NEDGES + 1024);           // 3*8192 (bf16 W^T)

  k_wprep<<<NLAYERS + 1, 256, 0, stream>>>(W, Wt, batch, goff, gsum, bcnt);
  // layer-0 GEMM overlapped with radix pass A
  k_front<<<GEMMB + RADB, 256, 0, stream>>>(x, Wt, a_s, a_d, Hb, as_, ad_, ei,
                                            bh, bcnt);
  k_bscan<<<1, 256, 0, stream>>>(bcnt, bstart);
  k_passB<<<RADB, 256, 0, stream>>>(ei, bstart, bh, ebuf);
  k_passC<<<NB, 256, 0, stream>>>(ebuf, bstart, row_ptr, csr);

  for (int l = 0; l < NLAYERS; ++l) {
    if (l > 0) {
      k_gemm<<<GEMMB, 256, 0, stream>>>(xb, Wt + (size_t)l * FDIM * FDIM / 2,
                                        a_s + l * FDIM, a_d + l * FDIM, Hb,
                                        as_, ad_);
    }
    k_aggregate<<<(NNODES + 3) / 4, 256, 0, stream>>>(
        Hb, as_, ad_, row_ptr, csr, bias + l * FDIM, xb);
  }
  k_pool2<<<NGRAPH * PCH, 256, 0, stream>>>(xb, goff, gsum);
  k_final<<<1, 64, 0, stream>>>(gsum, goff, lw, lb, out);
}